// Round 15
// baseline (54.725 us; speedup 1.0000x reference)
//
#include <hip/hip_runtime.h>

#define BB 16
#define QQ 64
#define KK 512
#define DD 256
#define HH 256
#define KTILE 128
#define NZ 4
#define LDST 56   // proj LDS row stride (bf16 elems)

#define LOG2E2 2.88539008177792681f   // 2*log2(e): exp2(LOG2E2*x) = e^{2x}

typedef unsigned int uint;
typedef unsigned short ushort;
typedef __attribute__((ext_vector_type(8))) short bf16x8;
typedef __attribute__((ext_vector_type(8))) unsigned short ushort8;
typedef __attribute__((ext_vector_type(4))) float f32x4;

__device__ __forceinline__ float fast_exp2(float x) {
#if __has_builtin(__builtin_amdgcn_exp2f)
    return __builtin_amdgcn_exp2f(x);
#else
    return exp2f(x);
#endif
}

__device__ __forceinline__ ushort f32_to_bf16_rtne(float x) {
    uint u = __float_as_uint(x);
    u = (u + 0x7FFFu + ((u >> 16) & 1u)) >> 16;
    return (ushort)u;
}

// unpack 8 bf16 (uint4) -> two float4
__device__ __forceinline__ void cvt8(uint4 u, float4& a, float4& b) {
    a.x = __uint_as_float(u.x << 16); a.y = __uint_as_float(u.x & 0xFFFF0000u);
    a.z = __uint_as_float(u.y << 16); a.w = __uint_as_float(u.y & 0xFFFF0000u);
    b.x = __uint_as_float(u.z << 16); b.y = __uint_as_float(u.z & 0xFFFF0000u);
    b.z = __uint_as_float(u.w << 16); b.w = __uint_as_float(u.w & 0xFFFF0000u);
}

// ---------------------------------------------------------------------------
// MFMA bf16 projections (R13-verified). Y = (X @ W) * 2log2e.
// ---------------------------------------------------------------------------
__global__ __launch_bounds__(256) void proj_both(
        const float* __restrict__ Xq, const float* __restrict__ Wq, float* __restrict__ Yq,
        const float* __restrict__ Xk, const float* __restrict__ Wk, ushort* __restrict__ Yk16,
        const int* __restrict__ valid_lens) {
    __shared__ ushort As[64 * LDST];
    __shared__ ushort Bt[64 * LDST];
    const int rt = blockIdx.x;
    const bool is_q = (rt < 16);
    const float* X; const float* W; int row0;
    if (is_q) { X = Xq; W = Wq; row0 = rt * 64; }
    else {
        X = Xk; W = Wk; row0 = (rt - 16) * 64;
        const int bb    = row0 >> 9;
        const int local = row0 & 511;
        if (local >= valid_lens[bb]) return;
    }
    const int col0 = blockIdx.y * 64;
    const int tid  = threadIdx.x;
    const int lane = tid & 63;
    const int w    = tid >> 6;

    f32x4 acc[4] = {{0.f,0.f,0.f,0.f}, {0.f,0.f,0.f,0.f},
                    {0.f,0.f,0.f,0.f}, {0.f,0.f,0.f,0.f}};

    const int ar = tid >> 2;
    const int ak = (tid & 3) * 8;
    const int bc = tid & 15;
    const int bk = tid >> 4;

    for (int k0 = 0; k0 < HH; k0 += 32) {
        {
            const float* xp = X + (size_t)(row0 + ar) * HH + k0 + ak;
            float4 x0 = *(const float4*)(xp);
            float4 x1 = *(const float4*)(xp + 4);
            ushort8 o;
            o[0] = f32_to_bf16_rtne(x0.x); o[1] = f32_to_bf16_rtne(x0.y);
            o[2] = f32_to_bf16_rtne(x0.z); o[3] = f32_to_bf16_rtne(x0.w);
            o[4] = f32_to_bf16_rtne(x1.x); o[5] = f32_to_bf16_rtne(x1.y);
            o[6] = f32_to_bf16_rtne(x1.z); o[7] = f32_to_bf16_rtne(x1.w);
            *(ushort8*)(&As[ar * LDST + ak]) = o;
        }
        {
            #pragma unroll
            for (int s = 0; s < 2; ++s) {
                float4 wv = *(const float4*)(W + (size_t)(k0 + bk + 16*s) * HH + col0 + bc*4);
                Bt[(bc*4 + 0) * LDST + bk + 16*s] = f32_to_bf16_rtne(wv.x);
                Bt[(bc*4 + 1) * LDST + bk + 16*s] = f32_to_bf16_rtne(wv.y);
                Bt[(bc*4 + 2) * LDST + bk + 16*s] = f32_to_bf16_rtne(wv.z);
                Bt[(bc*4 + 3) * LDST + bk + 16*s] = f32_to_bf16_rtne(wv.w);
            }
        }
        __syncthreads();

        const bf16x8 af = *(const bf16x8*)(&As[(w*16 + (lane & 15)) * LDST + (lane >> 4) * 8]);
        #pragma unroll
        for (int ct = 0; ct < 4; ++ct) {
            const bf16x8 bf = *(const bf16x8*)(&Bt[(ct*16 + (lane & 15)) * LDST + (lane >> 4) * 8]);
            acc[ct] = __builtin_amdgcn_mfma_f32_16x16x32_bf16(af, bf, acc[ct], 0, 0, 0);
        }
        __syncthreads();
    }

    const int orow = row0 + w*16 + (lane >> 4) * 4;
    const int ocol = col0 + (lane & 15);
    if (is_q) {
        #pragma unroll
        for (int ct = 0; ct < 4; ++ct)
            #pragma unroll
            for (int j = 0; j < 4; ++j)
                Yq[(size_t)(orow + j) * HH + ocol + ct*16] = acc[ct][j] * LOG2E2;
    } else {
        #pragma unroll
        for (int ct = 0; ct < 4; ++ct)
            #pragma unroll
            for (int j = 0; j < 4; ++j)
                Yk16[(size_t)(orow + j) * HH + ocol + ct*16] =
                    f32_to_bf16_rtne(acc[ct][j] * LOG2E2);
    }
}

// ---------------------------------------------------------------------------
// Flash-style fused kernel, q-QUAD items. Grid 1024 static; item t=(tile,
// quad): tile_idx=t>>4, q0=(t&15)*4; t>=items exits (items=TT*16<=1024).
// 512 thr / 8 waves; wave strip = 16 k. q-block (4x256 f32) in bank-padded
// LDS qls[4][16][20] (2-way banks, free). Phase A: per g (4 k), unpack K
// once, two passes of 2 q from LDS -> 4x amortized K traffic; batched
// 4-chain shfl reduce. Phase B: waves 0-3, one q-row each. Phase C: 8 wave
// strips, V row loaded once used 4x; red[8][4][DD] reduce -> po.
// ---------------------------------------------------------------------------
__global__ __launch_bounds__(512) void fused_flash(
        const float* __restrict__ qf, const ushort* __restrict__ kf16,
        const float* __restrict__ w_v, const int* __restrict__ valid_lens,
        const float* __restrict__ values,
        float* __restrict__ pm, float* __restrict__ pl, float* __restrict__ po) {
    __shared__ float qls[4][16][20];    // 5 KB q-block
    __shared__ float sc[4][KTILE];      // 2 KB scores
    __shared__ float pp[4][KTILE];      // 2 KB unnormalized probs
    __shared__ float red[8][4][DD];     // 32 KB PV partials

    // total active tiles
    int TT = 0;
    #pragma unroll
    for (int i = 0; i < BB; ++i)
        TT += (valid_lens[i] + KTILE - 1) >> 7;

    const int t = blockIdx.x;
    if (t >= TT * 16) return;
    const int tile_idx = t >> 4;
    const int q0       = (t & 15) * 4;

    const int tid  = threadIdx.x;
    const int lane = tid & 63;
    const int w    = tid >> 6;          // 0..7
    const int hg   = lane & 15;
    const int ksub = lane >> 4;
    const int h0   = hg * 16;

    // map tile_idx -> (b, z)
    int bb = 0, zz = 0, vlb = 1, acc = 0;
    #pragma unroll
    for (int i = 0; i < BB; ++i) {
        const int v   = valid_lens[i];
        const int nzi = (v + KTILE - 1) >> 7;
        const bool hit = (tile_idx >= acc) && (tile_idx < acc + nzi);
        if (hit) { bb = i; zz = tile_idx - acc; vlb = v; }
        acc += nzi;
    }
    const int tile_lo = zz * KTILE;
    const int tile_hi = (tile_lo + KTILE < vlb) ? (tile_lo + KTILE) : vlb;

    float4 nw[4];
    float wvsum = 0.f;
    #pragma unroll
    for (int i = 0; i < 4; ++i) {
        float4 wv4 = *(const float4*)(w_v + h0 + i*4);
        wvsum += ((wv4.x + wv4.y) + (wv4.z + wv4.w));
        nw[i] = make_float4(-2.f*wv4.x, -2.f*wv4.y, -2.f*wv4.z, -2.f*wv4.w);
    }

    {   // stage q-block: 512 thr, thread: q=tid>>7, s=tid&127 -> float2
        const int q = tid >> 7, s = tid & 127;
        const float* qp = qf + (size_t)(bb*QQ + q0 + q) * HH + s*2;
        float2 x = *(const float2*)(qp);
        qls[q][s >> 3][(s & 7) * 2]     = x.x;
        qls[q][s >> 3][(s & 7) * 2 + 1] = x.y;
    }
    sc[tid >> 7][tid & 127] = -1e6f;    // 512 slots exactly

    // wave strip: 16 k
    const int lo  = tile_lo + w * 16;
    int hi = lo + 16; hi = (hi > tile_hi) ? tile_hi : hi;
    const int cnt = hi - lo;
    const int ng  = (cnt <= 0) ? 0 : ((cnt + 3) >> 2);

    __syncthreads();

    // ---- Phase A: scores for 4 q over the strip ----
    {
        const size_t brows = (size_t)bb * KK;
        uint4 c0, c1;
        if (ng > 0) {
            int row = lo + ksub;
            row = (row < tile_hi) ? row : (tile_hi - 1);
            const ushort* p = kf16 + (brows + row) * HH + h0;
            c0 = *(const uint4*)(p);
            c1 = *(const uint4*)(p + 8);
        }
        for (int g = 0; g < ng; ++g) {
            uint4 n0, n1;
            const bool more = (g + 1 < ng);
            if (more) {
                int row = lo + (g+1)*4 + ksub;
                row = (row < tile_hi) ? row : (tile_hi - 1);
                const ushort* p = kf16 + (brows + row) * HH + h0;
                n0 = *(const uint4*)(p);
                n1 = *(const uint4*)(p + 8);
            }
            float4 kv[4];
            cvt8(c0, kv[0], kv[1]);
            cvt8(c1, kv[2], kv[3]);

            float s4[4];
            #pragma unroll
            for (int pass = 0; pass < 2; ++pass) {
                #pragma unroll
                for (int qi = 0; qi < 2; ++qi) {
                    const int q = pass*2 + qi;
                    float a0 = wvsum, a1 = 0.f, a2 = 0.f, a3 = 0.f;
                    #pragma unroll
                    for (int i = 0; i < 4; ++i) {
                        const float4 qv = *(const float4*)(&qls[q][hg][i*4]);
                        float e0 = fast_exp2(qv.x + kv[i].x);
                        float e1 = fast_exp2(qv.y + kv[i].y);
                        float e2 = fast_exp2(qv.z + kv[i].z);
                        float e3 = fast_exp2(qv.w + kv[i].w);
                        a0 = fmaf(nw[i].x, __builtin_amdgcn_rcpf(e0 + 1.f), a0);
                        a1 = fmaf(nw[i].y, __builtin_amdgcn_rcpf(e1 + 1.f), a1);
                        a2 = fmaf(nw[i].z, __builtin_amdgcn_rcpf(e2 + 1.f), a2);
                        a3 = fmaf(nw[i].w, __builtin_amdgcn_rcpf(e3 + 1.f), a3);
                    }
                    s4[pass*2 + qi] = (a0 + a1) + (a2 + a3);
                }
            }
            #pragma unroll
            for (int off = 8; off; off >>= 1) {
                #pragma unroll
                for (int qi = 0; qi < 4; ++qi)
                    s4[qi] += __shfl_xor(s4[qi], off);
            }
            const int k = lo + g*4 + ksub;
            if (hg == 0 && k < hi) {
                #pragma unroll
                for (int qi = 0; qi < 4; ++qi)
                    sc[qi][k - tile_lo] = s4[qi];
            }
            if (more) { c0 = n0; c1 = n1; }
        }
    }
    __syncthreads();

    // ---- Phase B: per-row tile max/sum + unnormalized p (waves 0..3) ----
    if (w < 4) {
        const int q = w;
        float s0 = sc[q][lane*2], s1 = sc[q][lane*2 + 1];
        float m = fmaxf(s0, s1);
        #pragma unroll
        for (int off = 32; off; off >>= 1) m = fmaxf(m, __shfl_xor(m, off));
        float p0 = __expf(s0 - m), p1 = __expf(s1 - m);
        float l = p0 + p1;
        #pragma unroll
        for (int off = 32; off; off >>= 1) l += __shfl_xor(l, off);
        pp[q][lane*2]     = p0;
        pp[q][lane*2 + 1] = p1;
        if (lane == 0) {
            const int id = ((bb*QQ + q0 + q) << 2) + zz;
            pm[id] = m; pl[id] = l;
        }
    }
    __syncthreads();

    // ---- Phase C: PV over the strip, V row loaded once, 4 q in regs ----
    {
        const float* V = values + (size_t)bb * KK * DD + lane*4;
        float4 a0 = make_float4(0.f,0.f,0.f,0.f);
        float4 a1 = a0, a2 = a0, a3 = a0;
        for (int k = lo; k < hi; ++k) {
            const int kt = k - tile_lo;
            float4 v4 = *(const float4*)(V + (size_t)k * DD);
            const float w0 = pp[0][kt], w1 = pp[1][kt];
            const float w2 = pp[2][kt], w3 = pp[3][kt];
            a0.x = fmaf(w0, v4.x, a0.x); a0.y = fmaf(w0, v4.y, a0.y);
            a0.z = fmaf(w0, v4.z, a0.z); a0.w = fmaf(w0, v4.w, a0.w);
            a1.x = fmaf(w1, v4.x, a1.x); a1.y = fmaf(w1, v4.y, a1.y);
            a1.z = fmaf(w1, v4.z, a1.z); a1.w = fmaf(w1, v4.w, a1.w);
            a2.x = fmaf(w2, v4.x, a2.x); a2.y = fmaf(w2, v4.y, a2.y);
            a2.z = fmaf(w2, v4.z, a2.z); a2.w = fmaf(w2, v4.w, a2.w);
            a3.x = fmaf(w3, v4.x, a3.x); a3.y = fmaf(w3, v4.y, a3.y);
            a3.z = fmaf(w3, v4.z, a3.z); a3.w = fmaf(w3, v4.w, a3.w);
        }
        *(float4*)(&red[w][0][lane*4]) = a0;
        *(float4*)(&red[w][1][lane*4]) = a1;
        *(float4*)(&red[w][2][lane*4]) = a2;
        *(float4*)(&red[w][3][lane*4]) = a3;
    }
    __syncthreads();

    // ---- po writes: 4 q x 256 d = 1024 outputs / 512 thr = 2 each ----
    #pragma unroll
    for (int i = 0; i < 2; ++i) {
        const int slot = tid + i*512;
        const int q = slot >> 8, d = slot & 255;
        float o = 0.f;
        #pragma unroll
        for (int ww = 0; ww < 8; ++ww) o += red[ww][q][d];
        po[(size_t)(((bb*QQ + q0 + q) << 2) + zz) * DD + d] = o;
    }
}

// ---------------------------------------------------------------------------
// Combine <=4 tile partials per (b,q): online-softmax merge. grid (B,Q), 256.
// ---------------------------------------------------------------------------
__global__ __launch_bounds__(256) void combine_kernel(
        const float* __restrict__ pm, const float* __restrict__ pl,
        const float* __restrict__ po, const int* __restrict__ valid_lens,
        float* __restrict__ out) {
    const int b   = blockIdx.x;
    const int q   = blockIdx.y;
    const int tid = threadIdx.x;
    const int vl  = valid_lens[b];
    const int nz  = (vl + KTILE - 1) >> 7;
    const int idx4 = (b*QQ + q) << 2;

    float mz[NZ], wz[NZ];
    float M = -3.0e38f;
    #pragma unroll
    for (int z = 0; z < NZ; ++z) {
        mz[z] = (z < nz) ? pm[idx4 + z] : -3.0e38f;
        M = fmaxf(M, mz[z]);
    }
    float L = 0.f;
    #pragma unroll
    for (int z = 0; z < NZ; ++z) {
        wz[z] = (z < nz) ? __expf(mz[z] - M) : 0.f;
        L = fmaf(wz[z], (z < nz) ? pl[idx4 + z] : 0.f, L);
    }
    const float inv = 1.f / L;

    float o = 0.f;
    #pragma unroll
    for (int z = 0; z < NZ; ++z) {
        if (z < nz)
            o = fmaf(wz[z], po[(size_t)(idx4 + z) * DD + tid], o);
    }
    out[(size_t)(b*QQ + q) * DD + tid] = o * inv;
}

extern "C" void kernel_launch(void* const* d_in, const int* in_sizes, int n_in,
                              void* d_out, int out_size, void* d_ws, size_t ws_size,
                              hipStream_t stream) {
    (void)in_sizes; (void)n_in; (void)out_size; (void)ws_size;
    const float* querys     = (const float*)d_in[0];
    const float* keys       = (const float*)d_in[1];
    const float* values     = (const float*)d_in[2];
    const int*   valid_lens = (const int*)d_in[3];
    const float* Wq         = (const float*)d_in[4];
    const float* Wk         = (const float*)d_in[5];
    const float* w_v        = (const float*)d_in[6];
    float* out = (float*)d_out;

    float*  qf    = (float*)d_ws;                          // 1 MB f32 (pre-scaled)
    ushort* kfeat = (ushort*)(qf + (size_t)BB*QQ*HH);      // 4 MB bf16 (pre-scaled)
    float*  pm    = (float*)(kfeat + (size_t)BB*KK*HH);    // 16 KB
    float*  pl    = pm + BB*QQ*NZ;                         // 16 KB
    float*  po    = pl + BB*QQ*NZ;                         // 4 MB

    proj_both<<<dim3(16 + BB*KK/64, HH/64), 256, 0, stream>>>(
        querys, Wq, qf, keys, Wk, kfeat, valid_lens);
    fused_flash<<<dim3(1024), 512, 0, stream>>>(
        qf, kfeat, w_v, valid_lens, values, pm, pl, po);
    combine_kernel<<<dim3(BB, QQ), 256, 0, stream>>>(
        pm, pl, po, valid_lens, out);
}

// Round 16
// 44.261 us; speedup vs baseline: 1.2364x; 1.2364x over previous
//
#include <hip/hip_runtime.h>

#define BB 16
#define QQ 64
#define KK 512
#define DD 256
#define HH 256
#define KTILE 128
#define NZ 4
#define PERSIST 2048
#define LDST 56   // proj LDS row stride (bf16 elems)

#define LOG2E2 2.88539008177792681f   // 2*log2(e): exp2(LOG2E2*x) = e^{2x}

typedef unsigned int uint;
typedef unsigned short ushort;
typedef __attribute__((ext_vector_type(8))) short bf16x8;
typedef __attribute__((ext_vector_type(8))) unsigned short ushort8;
typedef __attribute__((ext_vector_type(4))) float f32x4;

__device__ __forceinline__ float fast_exp2(float x) {
#if __has_builtin(__builtin_amdgcn_exp2f)
    return __builtin_amdgcn_exp2f(x);
#else
    return exp2f(x);
#endif
}

__device__ __forceinline__ ushort f32_to_bf16_rtne(float x) {
    uint u = __float_as_uint(x);
    u = (u + 0x7FFFu + ((u >> 16) & 1u)) >> 16;
    return (ushort)u;
}

// unpack 8 bf16 (uint4) -> two float4
__device__ __forceinline__ void cvt8(uint4 u, float4& a, float4& b) {
    a.x = __uint_as_float(u.x << 16); a.y = __uint_as_float(u.x & 0xFFFF0000u);
    a.z = __uint_as_float(u.y << 16); a.w = __uint_as_float(u.y & 0xFFFF0000u);
    b.x = __uint_as_float(u.z << 16); b.y = __uint_as_float(u.z & 0xFFFF0000u);
    b.z = __uint_as_float(u.w << 16); b.w = __uint_as_float(u.w & 0xFFFF0000u);
}

// ---------------------------------------------------------------------------
// MFMA bf16 projections (R13-verified). Y = (X @ W) * 2log2e.
// ---------------------------------------------------------------------------
__global__ __launch_bounds__(256) void proj_both(
        const float* __restrict__ Xq, const float* __restrict__ Wq, float* __restrict__ Yq,
        const float* __restrict__ Xk, const float* __restrict__ Wk, ushort* __restrict__ Yk16,
        const int* __restrict__ valid_lens) {
    __shared__ ushort As[64 * LDST];
    __shared__ ushort Bt[64 * LDST];
    const int rt = blockIdx.x;
    const bool is_q = (rt < 16);
    const float* X; const float* W; int row0;
    if (is_q) { X = Xq; W = Wq; row0 = rt * 64; }
    else {
        X = Xk; W = Wk; row0 = (rt - 16) * 64;
        const int bb    = row0 >> 9;
        const int local = row0 & 511;
        if (local >= valid_lens[bb]) return;
    }
    const int col0 = blockIdx.y * 64;
    const int tid  = threadIdx.x;
    const int lane = tid & 63;
    const int w    = tid >> 6;

    f32x4 acc[4] = {{0.f,0.f,0.f,0.f}, {0.f,0.f,0.f,0.f},
                    {0.f,0.f,0.f,0.f}, {0.f,0.f,0.f,0.f}};

    const int ar = tid >> 2;
    const int ak = (tid & 3) * 8;
    const int bc = tid & 15;
    const int bk = tid >> 4;

    for (int k0 = 0; k0 < HH; k0 += 32) {
        {
            const float* xp = X + (size_t)(row0 + ar) * HH + k0 + ak;
            float4 x0 = *(const float4*)(xp);
            float4 x1 = *(const float4*)(xp + 4);
            ushort8 o;
            o[0] = f32_to_bf16_rtne(x0.x); o[1] = f32_to_bf16_rtne(x0.y);
            o[2] = f32_to_bf16_rtne(x0.z); o[3] = f32_to_bf16_rtne(x0.w);
            o[4] = f32_to_bf16_rtne(x1.x); o[5] = f32_to_bf16_rtne(x1.y);
            o[6] = f32_to_bf16_rtne(x1.z); o[7] = f32_to_bf16_rtne(x1.w);
            *(ushort8*)(&As[ar * LDST + ak]) = o;
        }
        {
            #pragma unroll
            for (int s = 0; s < 2; ++s) {
                float4 wv = *(const float4*)(W + (size_t)(k0 + bk + 16*s) * HH + col0 + bc*4);
                Bt[(bc*4 + 0) * LDST + bk + 16*s] = f32_to_bf16_rtne(wv.x);
                Bt[(bc*4 + 1) * LDST + bk + 16*s] = f32_to_bf16_rtne(wv.y);
                Bt[(bc*4 + 2) * LDST + bk + 16*s] = f32_to_bf16_rtne(wv.z);
                Bt[(bc*4 + 3) * LDST + bk + 16*s] = f32_to_bf16_rtne(wv.w);
            }
        }
        __syncthreads();

        const bf16x8 af = *(const bf16x8*)(&As[(w*16 + (lane & 15)) * LDST + (lane >> 4) * 8]);
        #pragma unroll
        for (int ct = 0; ct < 4; ++ct) {
            const bf16x8 bf = *(const bf16x8*)(&Bt[(ct*16 + (lane & 15)) * LDST + (lane >> 4) * 8]);
            acc[ct] = __builtin_amdgcn_mfma_f32_16x16x32_bf16(af, bf, acc[ct], 0, 0, 0);
        }
        __syncthreads();
    }

    const int orow = row0 + w*16 + (lane >> 4) * 4;
    const int ocol = col0 + (lane & 15);
    if (is_q) {
        #pragma unroll
        for (int ct = 0; ct < 4; ++ct)
            #pragma unroll
            for (int j = 0; j < 4; ++j)
                Yq[(size_t)(orow + j) * HH + ocol + ct*16] = acc[ct][j] * LOG2E2;
    } else {
        #pragma unroll
        for (int ct = 0; ct < 4; ++ct)
            #pragma unroll
            for (int j = 0; j < 4; ++j)
                Yk16[(size_t)(orow + j) * HH + ocol + ct*16] =
                    f32_to_bf16_rtne(acc[ct][j] * LOG2E2);
    }
}

// ---------------------------------------------------------------------------
// Persistent flash-style fused kernel, q-pair items (R12/R13 structure),
// Phase A K-prefetch depth 2 (two loads in flight per wave).
// ---------------------------------------------------------------------------
__global__ __launch_bounds__(256) void fused_flash(
        const float* __restrict__ qf, const ushort* __restrict__ kf16,
        const float* __restrict__ w_v, const int* __restrict__ valid_lens,
        const float* __restrict__ values,
        float* __restrict__ pm, float* __restrict__ pl, float* __restrict__ po) {
    __shared__ float sc[2][KTILE];
    __shared__ float pp[2][KTILE];
    __shared__ float red[4][2][DD];

    const int tid  = threadIdx.x;
    const int lane = tid & 63;
    const int w    = tid >> 6;
    const int hg   = lane & 15;
    const int ksub = lane >> 4;
    const int h0   = hg * 16;

    float4 nw[4];
    float wvsum = 0.f;
    #pragma unroll
    for (int i = 0; i < 4; ++i) {
        float4 wv4 = *(const float4*)(w_v + h0 + i*4);
        wvsum += ((wv4.x + wv4.y) + (wv4.z + wv4.w));
        nw[i] = make_float4(-2.f*wv4.x, -2.f*wv4.y, -2.f*wv4.z, -2.f*wv4.w);
    }

    int TT = 0;
    #pragma unroll
    for (int i = 0; i < BB; ++i)
        TT += (valid_lens[i] + KTILE - 1) >> 7;
    const int items = TT * 32;
    const int qch   = items >> 11;
    const int rch   = items & 2047;
    const int bid   = blockIdx.x;
    const int lo_it = bid * qch + ((bid < rch) ? bid : rch);
    const int n_it  = qch + ((bid < rch) ? 1 : 0);

    for (int t = lo_it; t < lo_it + n_it; ++t) {
        const int tile_idx = t >> 5;
        const int q0       = (t & 31) * 2;

        int bb = 0, zz = 0, vlb = 1, acc = 0;
        #pragma unroll
        for (int i = 0; i < BB; ++i) {
            const int v   = valid_lens[i];
            const int nzi = (v + KTILE - 1) >> 7;
            const bool hit = (tile_idx >= acc) && (tile_idx < acc + nzi);
            if (hit) { bb = i; zz = tile_idx - acc; vlb = v; }
            acc += nzi;
        }

        const int tile_lo = zz * KTILE;
        const int tile_hi = (tile_lo + KTILE < vlb) ? (tile_lo + KTILE) : vlb;

        sc[tid >> 7][tid & 127] = -1e6f;

        float4 qA[4], qB[4];
        {
            const float* qrA = qf + (size_t)(bb*QQ + q0) * HH + h0;
            const float* qrB = qrA + HH;
            #pragma unroll
            for (int i = 0; i < 4; ++i) {
                qA[i] = *(const float4*)(qrA + i*4);
                qB[i] = *(const float4*)(qrB + i*4);
            }
        }

        const int lo  = tile_lo + w * 32;
        int hi = lo + 32; hi = (hi > tile_hi) ? tile_hi : hi;
        const int cnt = hi - lo;
        const int ng  = (cnt <= 0) ? 0 : ((cnt + 3) >> 2);

        __syncthreads();

        {   // Phase A: scores for both q, prefetch depth 2
            const size_t brows = (size_t)bb * KK;
            auto ldrow = [&](int g, uint4& u0, uint4& u1) {
                int row = lo + g*4 + ksub;
                row = (row < tile_hi) ? row : (tile_hi - 1);
                const ushort* p = kf16 + (brows + row) * HH + h0;
                u0 = *(const uint4*)(p);
                u1 = *(const uint4*)(p + 8);
            };
            uint4 c0, c1, d0, d1;
            if (ng > 0) ldrow(0, c0, c1);
            if (ng > 1) ldrow(1, d0, d1);

            for (int g = 0; g < ng; ++g) {
                uint4 n0, n1;
                if (g + 2 < ng) ldrow(g + 2, n0, n1);

                float4 kv[4];
                cvt8(c0, kv[0], kv[1]);
                cvt8(c1, kv[2], kv[3]);

                float a0 = wvsum, a1 = 0.f, a2 = 0.f, a3 = 0.f;
                float b0 = wvsum, b1 = 0.f, b2 = 0.f, b3 = 0.f;
                #pragma unroll
                for (int i = 0; i < 4; ++i) {
                    float eA0 = fast_exp2(qA[i].x + kv[i].x);
                    float eA1 = fast_exp2(qA[i].y + kv[i].y);
                    float eA2 = fast_exp2(qA[i].z + kv[i].z);
                    float eA3 = fast_exp2(qA[i].w + kv[i].w);
                    a0 = fmaf(nw[i].x, __builtin_amdgcn_rcpf(eA0 + 1.f), a0);
                    a1 = fmaf(nw[i].y, __builtin_amdgcn_rcpf(eA1 + 1.f), a1);
                    a2 = fmaf(nw[i].z, __builtin_amdgcn_rcpf(eA2 + 1.f), a2);
                    a3 = fmaf(nw[i].w, __builtin_amdgcn_rcpf(eA3 + 1.f), a3);
                    float eB0 = fast_exp2(qB[i].x + kv[i].x);
                    float eB1 = fast_exp2(qB[i].y + kv[i].y);
                    float eB2 = fast_exp2(qB[i].z + kv[i].z);
                    float eB3 = fast_exp2(qB[i].w + kv[i].w);
                    b0 = fmaf(nw[i].x, __builtin_amdgcn_rcpf(eB0 + 1.f), b0);
                    b1 = fmaf(nw[i].y, __builtin_amdgcn_rcpf(eB1 + 1.f), b1);
                    b2 = fmaf(nw[i].z, __builtin_amdgcn_rcpf(eB2 + 1.f), b2);
                    b3 = fmaf(nw[i].w, __builtin_amdgcn_rcpf(eB3 + 1.f), b3);
                }
                float sA = (a0 + a1) + (a2 + a3);
                float sB = (b0 + b1) + (b2 + b3);
                #pragma unroll
                for (int off = 8; off; off >>= 1) {
                    sA += __shfl_xor(sA, off);
                    sB += __shfl_xor(sB, off);
                }
                const int k = lo + g*4 + ksub;
                if (hg == 0 && k < hi) {
                    sc[0][k - tile_lo] = sA;
                    sc[1][k - tile_lo] = sB;
                }
                c0 = d0; c1 = d1;
                d0 = n0; d1 = n1;
            }
        }
        __syncthreads();

        if (w < 2) {   // Phase B
            float s0 = sc[w][lane*2], s1 = sc[w][lane*2 + 1];
            float m = fmaxf(s0, s1);
            #pragma unroll
            for (int off = 32; off; off >>= 1) m = fmaxf(m, __shfl_xor(m, off));
            float p0 = __expf(s0 - m), p1 = __expf(s1 - m);
            float l = p0 + p1;
            #pragma unroll
            for (int off = 32; off; off >>= 1) l += __shfl_xor(l, off);
            pp[w][lane*2]     = p0;
            pp[w][lane*2 + 1] = p1;
            if (lane == 0) {
                const int id = ((bb*QQ + q0 + w) << 2) + zz;
                pm[id] = m; pl[id] = l;
            }
        }
        __syncthreads();

        {   // Phase C: PV partial, f32 V, both q
            const float* V = values + (size_t)bb * KK * DD + lane*4;
            float4 aA = make_float4(0.f,0.f,0.f,0.f);
            float4 aB = aA;
            #pragma unroll 4
            for (int k = lo; k < hi; ++k) {
                const float pA = pp[0][k - tile_lo];
                const float pB = pp[1][k - tile_lo];
                float4 v4 = *(const float4*)(V + (size_t)k * DD);
                aA.x = fmaf(pA, v4.x, aA.x); aA.y = fmaf(pA, v4.y, aA.y);
                aA.z = fmaf(pA, v4.z, aA.z); aA.w = fmaf(pA, v4.w, aA.w);
                aB.x = fmaf(pB, v4.x, aB.x); aB.y = fmaf(pB, v4.y, aB.y);
                aB.z = fmaf(pB, v4.z, aB.z); aB.w = fmaf(pB, v4.w, aB.w);
            }
            *(float4*)(&red[w][0][lane*4]) = aA;
            *(float4*)(&red[w][1][lane*4]) = aB;
        }
        __syncthreads();

        #pragma unroll
        for (int i = 0; i < 2; ++i) {
            const int idx = tid + i*256;
            const int qq = idx >> 8, d = idx & 255;
            const float o = (red[0][qq][d] + red[1][qq][d])
                          + (red[2][qq][d] + red[3][qq][d]);
            po[(size_t)(((bb*QQ + q0 + qq) << 2) + zz) * DD + d] = o;
        }
        __syncthreads();
    }
}

// ---------------------------------------------------------------------------
// Combine <=4 tile partials per (b,q): online-softmax merge. grid (B,Q), 256.
// ---------------------------------------------------------------------------
__global__ __launch_bounds__(256) void combine_kernel(
        const float* __restrict__ pm, const float* __restrict__ pl,
        const float* __restrict__ po, const int* __restrict__ valid_lens,
        float* __restrict__ out) {
    const int b   = blockIdx.x;
    const int q   = blockIdx.y;
    const int tid = threadIdx.x;
    const int vl  = valid_lens[b];
    const int nz  = (vl + KTILE - 1) >> 7;
    const int idx4 = (b*QQ + q) << 2;

    float mz[NZ], wz[NZ];
    float M = -3.0e38f;
    #pragma unroll
    for (int z = 0; z < NZ; ++z) {
        mz[z] = (z < nz) ? pm[idx4 + z] : -3.0e38f;
        M = fmaxf(M, mz[z]);
    }
    float L = 0.f;
    #pragma unroll
    for (int z = 0; z < NZ; ++z) {
        wz[z] = (z < nz) ? __expf(mz[z] - M) : 0.f;
        L = fmaf(wz[z], (z < nz) ? pl[idx4 + z] : 0.f, L);
    }
    const float inv = 1.f / L;

    float o = 0.f;
    #pragma unroll
    for (int z = 0; z < NZ; ++z) {
        if (z < nz)
            o = fmaf(wz[z], po[(size_t)(idx4 + z) * DD + tid], o);
    }
    out[(size_t)(b*QQ + q) * DD + tid] = o * inv;
}

extern "C" void kernel_launch(void* const* d_in, const int* in_sizes, int n_in,
                              void* d_out, int out_size, void* d_ws, size_t ws_size,
                              hipStream_t stream) {
    (void)in_sizes; (void)n_in; (void)out_size; (void)ws_size;
    const float* querys     = (const float*)d_in[0];
    const float* keys       = (const float*)d_in[1];
    const float* values     = (const float*)d_in[2];
    const int*   valid_lens = (const int*)d_in[3];
    const float* Wq         = (const float*)d_in[4];
    const float* Wk         = (const float*)d_in[5];
    const float* w_v        = (const float*)d_in[6];
    float* out = (float*)d_out;

    float*  qf    = (float*)d_ws;                          // 1 MB f32 (pre-scaled)
    ushort* kfeat = (ushort*)(qf + (size_t)BB*QQ*HH);      // 4 MB bf16 (pre-scaled)
    float*  pm    = (float*)(kfeat + (size_t)BB*KK*HH);    // 16 KB
    float*  pl    = pm + BB*QQ*NZ;                         // 16 KB
    float*  po    = pl + BB*QQ*NZ;                         // 4 MB

    proj_both<<<dim3(16 + BB*KK/64, HH/64), 256, 0, stream>>>(
        querys, Wq, qf, keys, Wk, kfeat, valid_lens);
    fused_flash<<<dim3(PERSIST), 256, 0, stream>>>(
        qf, kfeat, w_v, valid_lens, values, pm, pl, po);
    combine_kernel<<<dim3(BB, QQ), 256, 0, stream>>>(
        pm, pl, po, valid_lens, out);
}

// Round 17
// 43.368 us; speedup vs baseline: 1.2619x; 1.0206x over previous
//
#include <hip/hip_runtime.h>

#define BB 16
#define QQ 64
#define KK 512
#define DD 256
#define HH 256
#define KTILE 128
#define NZ 4
#define LDST 56   // proj LDS row stride (bf16 elems)

#define LOG2E2 2.88539008177792681f   // 2*log2(e): exp2(LOG2E2*x) = e^{2x}

typedef unsigned int uint;
typedef unsigned short ushort;
typedef __attribute__((ext_vector_type(8))) short bf16x8;
typedef __attribute__((ext_vector_type(8))) unsigned short ushort8;
typedef __attribute__((ext_vector_type(4))) float f32x4;

__device__ __forceinline__ float fast_exp2(float x) {
#if __has_builtin(__builtin_amdgcn_exp2f)
    return __builtin_amdgcn_exp2f(x);
#else
    return exp2f(x);
#endif
}

__device__ __forceinline__ ushort f32_to_bf16_rtne(float x) {
    uint u = __float_as_uint(x);
    u = (u + 0x7FFFu + ((u >> 16) & 1u)) >> 16;
    return (ushort)u;
}

// unpack 8 bf16 (uint4) -> two float4
__device__ __forceinline__ void cvt8(uint4 u, float4& a, float4& b) {
    a.x = __uint_as_float(u.x << 16); a.y = __uint_as_float(u.x & 0xFFFF0000u);
    a.z = __uint_as_float(u.y << 16); a.w = __uint_as_float(u.y & 0xFFFF0000u);
    b.x = __uint_as_float(u.z << 16); b.y = __uint_as_float(u.z & 0xFFFF0000u);
    b.z = __uint_as_float(u.w << 16); b.w = __uint_as_float(u.w & 0xFFFF0000u);
}

// ---------------------------------------------------------------------------
// MFMA bf16 projections (R13-verified). Y = (X @ W) * 2log2e.
// ---------------------------------------------------------------------------
__global__ __launch_bounds__(256) void proj_both(
        const float* __restrict__ Xq, const float* __restrict__ Wq, float* __restrict__ Yq,
        const float* __restrict__ Xk, const float* __restrict__ Wk, ushort* __restrict__ Yk16,
        const int* __restrict__ valid_lens) {
    __shared__ ushort As[64 * LDST];
    __shared__ ushort Bt[64 * LDST];
    const int rt = blockIdx.x;
    const bool is_q = (rt < 16);
    const float* X; const float* W; int row0;
    if (is_q) { X = Xq; W = Wq; row0 = rt * 64; }
    else {
        X = Xk; W = Wk; row0 = (rt - 16) * 64;
        const int bb    = row0 >> 9;
        const int local = row0 & 511;
        if (local >= valid_lens[bb]) return;
    }
    const int col0 = blockIdx.y * 64;
    const int tid  = threadIdx.x;
    const int lane = tid & 63;
    const int w    = tid >> 6;

    f32x4 acc[4] = {{0.f,0.f,0.f,0.f}, {0.f,0.f,0.f,0.f},
                    {0.f,0.f,0.f,0.f}, {0.f,0.f,0.f,0.f}};

    const int ar = tid >> 2;
    const int ak = (tid & 3) * 8;
    const int bc = tid & 15;
    const int bk = tid >> 4;

    for (int k0 = 0; k0 < HH; k0 += 32) {
        {
            const float* xp = X + (size_t)(row0 + ar) * HH + k0 + ak;
            float4 x0 = *(const float4*)(xp);
            float4 x1 = *(const float4*)(xp + 4);
            ushort8 o;
            o[0] = f32_to_bf16_rtne(x0.x); o[1] = f32_to_bf16_rtne(x0.y);
            o[2] = f32_to_bf16_rtne(x0.z); o[3] = f32_to_bf16_rtne(x0.w);
            o[4] = f32_to_bf16_rtne(x1.x); o[5] = f32_to_bf16_rtne(x1.y);
            o[6] = f32_to_bf16_rtne(x1.z); o[7] = f32_to_bf16_rtne(x1.w);
            *(ushort8*)(&As[ar * LDST + ak]) = o;
        }
        {
            #pragma unroll
            for (int s = 0; s < 2; ++s) {
                float4 wv = *(const float4*)(W + (size_t)(k0 + bk + 16*s) * HH + col0 + bc*4);
                Bt[(bc*4 + 0) * LDST + bk + 16*s] = f32_to_bf16_rtne(wv.x);
                Bt[(bc*4 + 1) * LDST + bk + 16*s] = f32_to_bf16_rtne(wv.y);
                Bt[(bc*4 + 2) * LDST + bk + 16*s] = f32_to_bf16_rtne(wv.z);
                Bt[(bc*4 + 3) * LDST + bk + 16*s] = f32_to_bf16_rtne(wv.w);
            }
        }
        __syncthreads();

        const bf16x8 af = *(const bf16x8*)(&As[(w*16 + (lane & 15)) * LDST + (lane >> 4) * 8]);
        #pragma unroll
        for (int ct = 0; ct < 4; ++ct) {
            const bf16x8 bf = *(const bf16x8*)(&Bt[(ct*16 + (lane & 15)) * LDST + (lane >> 4) * 8]);
            acc[ct] = __builtin_amdgcn_mfma_f32_16x16x32_bf16(af, bf, acc[ct], 0, 0, 0);
        }
        __syncthreads();
    }

    const int orow = row0 + w*16 + (lane >> 4) * 4;
    const int ocol = col0 + (lane & 15);
    if (is_q) {
        #pragma unroll
        for (int ct = 0; ct < 4; ++ct)
            #pragma unroll
            for (int j = 0; j < 4; ++j)
                Yq[(size_t)(orow + j) * HH + ocol + ct*16] = acc[ct][j] * LOG2E2;
    } else {
        #pragma unroll
        for (int ct = 0; ct < 4; ++ct)
            #pragma unroll
            for (int j = 0; j < 4; ++j)
                Yk16[(size_t)(orow + j) * HH + ocol + ct*16] =
                    f32_to_bf16_rtne(acc[ct][j] * LOG2E2);
    }
}

// ---------------------------------------------------------------------------
// Flash-style fused kernel, q-pair items, XCD-PINNED at q-pair granularity.
// Grid 2048 = 8 XCDs x 256 slots (consecutive bids round-robin XCDs, so
// xcd = bid&7, slot = bid>>3). Slot s on XCD x: tile = x + 8*(s>>5)
// (ALL 32 q-pair items of a tile land on ONE XCD -> its 4MB L2 holds the
// tile's K 64KB + V 128KB; re-reads at L2 rate, not L3), qpair = s&31.
// Covers TT <= 64 tiles bijectively. Body identical to R13/R16 (prefetch
// depth 2, per-row softmax stats, f32 V PV amortized over 2 q).
// ---------------------------------------------------------------------------
__global__ __launch_bounds__(256) void fused_flash(
        const float* __restrict__ qf, const ushort* __restrict__ kf16,
        const float* __restrict__ w_v, const int* __restrict__ valid_lens,
        const float* __restrict__ values,
        float* __restrict__ pm, float* __restrict__ pl, float* __restrict__ po) {
    __shared__ float sc[2][KTILE];
    __shared__ float pp[2][KTILE];
    __shared__ float red[4][2][DD];

    const int tid  = threadIdx.x;
    const int lane = tid & 63;
    const int w    = tid >> 6;
    const int hg   = lane & 15;
    const int ksub = lane >> 4;
    const int h0   = hg * 16;

    // total active tiles
    int TT = 0;
    #pragma unroll
    for (int i = 0; i < BB; ++i)
        TT += (valid_lens[i] + KTILE - 1) >> 7;

    // XCD-pinned item mapping
    const int bid  = blockIdx.x;
    const int xcd  = bid & 7;
    const int slot = bid >> 3;            // 0..255
    const int tile_idx = xcd + 8 * (slot >> 5);
    if (tile_idx >= TT) return;
    const int q0 = (slot & 31) * 2;

    // map tile_idx -> (b, z) via unrolled prefix scan
    int bb = 0, zz = 0, vlb = 1, acc = 0;
    #pragma unroll
    for (int i = 0; i < BB; ++i) {
        const int v   = valid_lens[i];
        const int nzi = (v + KTILE - 1) >> 7;
        const bool hit = (tile_idx >= acc) && (tile_idx < acc + nzi);
        if (hit) { bb = i; zz = tile_idx - acc; vlb = v; }
        acc += nzi;
    }

    const int tile_lo = zz * KTILE;
    const int tile_hi = (tile_lo + KTILE < vlb) ? (tile_lo + KTILE) : vlb;

    float4 nw[4];
    float wvsum = 0.f;
    #pragma unroll
    for (int i = 0; i < 4; ++i) {
        float4 wv4 = *(const float4*)(w_v + h0 + i*4);
        wvsum += ((wv4.x + wv4.y) + (wv4.z + wv4.w));
        nw[i] = make_float4(-2.f*wv4.x, -2.f*wv4.y, -2.f*wv4.z, -2.f*wv4.w);
    }

    sc[tid >> 7][tid & 127] = -1e6f;

    float4 qA[4], qB[4];
    {
        const float* qrA = qf + (size_t)(bb*QQ + q0) * HH + h0;
        const float* qrB = qrA + HH;
        #pragma unroll
        for (int i = 0; i < 4; ++i) {
            qA[i] = *(const float4*)(qrA + i*4);
            qB[i] = *(const float4*)(qrB + i*4);
        }
    }

    const int lo  = tile_lo + w * 32;
    int hi = lo + 32; hi = (hi > tile_hi) ? tile_hi : hi;
    const int cnt = hi - lo;
    const int ng  = (cnt <= 0) ? 0 : ((cnt + 3) >> 2);

    __syncthreads();

    {   // Phase A: scores for both q, prefetch depth 2
        const size_t brows = (size_t)bb * KK;
        auto ldrow = [&](int g, uint4& u0, uint4& u1) {
            int row = lo + g*4 + ksub;
            row = (row < tile_hi) ? row : (tile_hi - 1);
            const ushort* p = kf16 + (brows + row) * HH + h0;
            u0 = *(const uint4*)(p);
            u1 = *(const uint4*)(p + 8);
        };
        uint4 c0, c1, d0, d1;
        if (ng > 0) ldrow(0, c0, c1);
        if (ng > 1) ldrow(1, d0, d1);

        for (int g = 0; g < ng; ++g) {
            uint4 n0, n1;
            if (g + 2 < ng) ldrow(g + 2, n0, n1);

            float4 kv[4];
            cvt8(c0, kv[0], kv[1]);
            cvt8(c1, kv[2], kv[3]);

            float a0 = wvsum, a1 = 0.f, a2 = 0.f, a3 = 0.f;
            float b0 = wvsum, b1 = 0.f, b2 = 0.f, b3 = 0.f;
            #pragma unroll
            for (int i = 0; i < 4; ++i) {
                float eA0 = fast_exp2(qA[i].x + kv[i].x);
                float eA1 = fast_exp2(qA[i].y + kv[i].y);
                float eA2 = fast_exp2(qA[i].z + kv[i].z);
                float eA3 = fast_exp2(qA[i].w + kv[i].w);
                a0 = fmaf(nw[i].x, __builtin_amdgcn_rcpf(eA0 + 1.f), a0);
                a1 = fmaf(nw[i].y, __builtin_amdgcn_rcpf(eA1 + 1.f), a1);
                a2 = fmaf(nw[i].z, __builtin_amdgcn_rcpf(eA2 + 1.f), a2);
                a3 = fmaf(nw[i].w, __builtin_amdgcn_rcpf(eA3 + 1.f), a3);
                float eB0 = fast_exp2(qB[i].x + kv[i].x);
                float eB1 = fast_exp2(qB[i].y + kv[i].y);
                float eB2 = fast_exp2(qB[i].z + kv[i].z);
                float eB3 = fast_exp2(qB[i].w + kv[i].w);
                b0 = fmaf(nw[i].x, __builtin_amdgcn_rcpf(eB0 + 1.f), b0);
                b1 = fmaf(nw[i].y, __builtin_amdgcn_rcpf(eB1 + 1.f), b1);
                b2 = fmaf(nw[i].z, __builtin_amdgcn_rcpf(eB2 + 1.f), b2);
                b3 = fmaf(nw[i].w, __builtin_amdgcn_rcpf(eB3 + 1.f), b3);
            }
            float sA = (a0 + a1) + (a2 + a3);
            float sB = (b0 + b1) + (b2 + b3);
            #pragma unroll
            for (int off = 8; off; off >>= 1) {
                sA += __shfl_xor(sA, off);
                sB += __shfl_xor(sB, off);
            }
            const int k = lo + g*4 + ksub;
            if (hg == 0 && k < hi) {
                sc[0][k - tile_lo] = sA;
                sc[1][k - tile_lo] = sB;
            }
            c0 = d0; c1 = d1;
            d0 = n0; d1 = n1;
        }
    }
    __syncthreads();

    if (w < 2) {   // Phase B
        float s0 = sc[w][lane*2], s1 = sc[w][lane*2 + 1];
        float m = fmaxf(s0, s1);
        #pragma unroll
        for (int off = 32; off; off >>= 1) m = fmaxf(m, __shfl_xor(m, off));
        float p0 = __expf(s0 - m), p1 = __expf(s1 - m);
        float l = p0 + p1;
        #pragma unroll
        for (int off = 32; off; off >>= 1) l += __shfl_xor(l, off);
        pp[w][lane*2]     = p0;
        pp[w][lane*2 + 1] = p1;
        if (lane == 0) {
            const int id = ((bb*QQ + q0 + w) << 2) + zz;
            pm[id] = m; pl[id] = l;
        }
    }
    __syncthreads();

    {   // Phase C: PV partial, f32 V, both q
        const float* V = values + (size_t)bb * KK * DD + lane*4;
        float4 aA = make_float4(0.f,0.f,0.f,0.f);
        float4 aB = aA;
        #pragma unroll 4
        for (int k = lo; k < hi; ++k) {
            const float pA = pp[0][k - tile_lo];
            const float pB = pp[1][k - tile_lo];
            float4 v4 = *(const float4*)(V + (size_t)k * DD);
            aA.x = fmaf(pA, v4.x, aA.x); aA.y = fmaf(pA, v4.y, aA.y);
            aA.z = fmaf(pA, v4.z, aA.z); aA.w = fmaf(pA, v4.w, aA.w);
            aB.x = fmaf(pB, v4.x, aB.x); aB.y = fmaf(pB, v4.y, aB.y);
            aB.z = fmaf(pB, v4.z, aB.z); aB.w = fmaf(pB, v4.w, aB.w);
        }
        *(float4*)(&red[w][0][lane*4]) = aA;
        *(float4*)(&red[w][1][lane*4]) = aB;
    }
    __syncthreads();

    #pragma unroll
    for (int i = 0; i < 2; ++i) {
        const int idx = tid + i*256;
        const int qq = idx >> 8, d = idx & 255;
        const float o = (red[0][qq][d] + red[1][qq][d])
                      + (red[2][qq][d] + red[3][qq][d]);
        po[(size_t)(((bb*QQ + q0 + qq) << 2) + zz) * DD + d] = o;
    }
}

// ---------------------------------------------------------------------------
// Combine <=4 tile partials per (b,q): online-softmax merge. grid (B,Q), 256.
// ---------------------------------------------------------------------------
__global__ __launch_bounds__(256) void combine_kernel(
        const float* __restrict__ pm, const float* __restrict__ pl,
        const float* __restrict__ po, const int* __restrict__ valid_lens,
        float* __restrict__ out) {
    const int b   = blockIdx.x;
    const int q   = blockIdx.y;
    const int tid = threadIdx.x;
    const int vl  = valid_lens[b];
    const int nz  = (vl + KTILE - 1) >> 7;
    const int idx4 = (b*QQ + q) << 2;

    float mz[NZ], wz[NZ];
    float M = -3.0e38f;
    #pragma unroll
    for (int z = 0; z < NZ; ++z) {
        mz[z] = (z < nz) ? pm[idx4 + z] : -3.0e38f;
        M = fmaxf(M, mz[z]);
    }
    float L = 0.f;
    #pragma unroll
    for (int z = 0; z < NZ; ++z) {
        wz[z] = (z < nz) ? __expf(mz[z] - M) : 0.f;
        L = fmaf(wz[z], (z < nz) ? pl[idx4 + z] : 0.f, L);
    }
    const float inv = 1.f / L;

    float o = 0.f;
    #pragma unroll
    for (int z = 0; z < NZ; ++z) {
        if (z < nz)
            o = fmaf(wz[z], po[(size_t)(idx4 + z) * DD + tid], o);
    }
    out[(size_t)(b*QQ + q) * DD + tid] = o * inv;
}

extern "C" void kernel_launch(void* const* d_in, const int* in_sizes, int n_in,
                              void* d_out, int out_size, void* d_ws, size_t ws_size,
                              hipStream_t stream) {
    (void)in_sizes; (void)n_in; (void)out_size; (void)ws_size;
    const float* querys     = (const float*)d_in[0];
    const float* keys       = (const float*)d_in[1];
    const float* values     = (const float*)d_in[2];
    const int*   valid_lens = (const int*)d_in[3];
    const float* Wq         = (const float*)d_in[4];
    const float* Wk         = (const float*)d_in[5];
    const float* w_v        = (const float*)d_in[6];
    float* out = (float*)d_out;

    float*  qf    = (float*)d_ws;                          // 1 MB f32 (pre-scaled)
    ushort* kfeat = (ushort*)(qf + (size_t)BB*QQ*HH);      // 4 MB bf16 (pre-scaled)
    float*  pm    = (float*)(kfeat + (size_t)BB*KK*HH);    // 16 KB
    float*  pl    = pm + BB*QQ*NZ;                         // 16 KB
    float*  po    = pl + BB*QQ*NZ;                         // 4 MB

    proj_both<<<dim3(16 + BB*KK/64, HH/64), 256, 0, stream>>>(
        querys, Wq, qf, keys, Wk, kfeat, valid_lens);
    fused_flash<<<dim3(2048), 256, 0, stream>>>(
        qf, kfeat, w_v, valid_lens, values, pm, pl, po);
    combine_kernel<<<dim3(BB, QQ), 256, 0, stream>>>(
        pm, pl, po, valid_lens, out);
}